// Round 6
// baseline (720.637 us; speedup 1.0000x reference)
//
#include <hip/hip_runtime.h>

#define BB 2
#define NN 32768
#define KK 16
#define DD 64
#define NC 10
#define NMOM 65   // 10 first moments + 55 unique second moments
#define NBLK1 256
#define BN_EPS 1e-6

__host__ __device__ __forceinline__ constexpr int pair_idx(int i, int j) {
    return 10 + i * 10 - (i * (i - 1)) / 2 + (j - i);
}

// ---------------- Kernel 1: concat-vector moment reduction ----------------
__global__ __launch_bounds__(256) void k_moments(
    const float* __restrict__ coords, const float* __restrict__ dist,
    const int* __restrict__ idx, float* __restrict__ partials)
{
    const int tid = threadIdx.x;
    const int bn = blockIdx.x * 256 + tid;          // 0 .. B*N-1
    const int b = bn >> 15;                          // N = 32768

    float acc[NMOM];
#pragma unroll
    for (int v = 0; v < NMOM; ++v) acc[v] = 0.f;

    const float cx = coords[(size_t)bn * 3 + 0];
    const float cy = coords[(size_t)bn * 3 + 1];
    const float cz = coords[(size_t)bn * 3 + 2];
    const float* cb = coords + (size_t)b * NN * 3;

    for (int k = 0; k < KK; ++k) {
        const int j = idx[(size_t)bn * KK + k];
        const float nx = cb[(size_t)j * 3 + 0];
        const float ny = cb[(size_t)j * 3 + 1];
        const float nz = cb[(size_t)j * 3 + 2];
        const float dd = dist[(size_t)bn * KK + k];
        const float c[NC] = {cx, cy, cz, nx, ny, nz, cx - nx, cy - ny, cz - nz, dd};
#pragma unroll
        for (int i = 0; i < NC; ++i) acc[i] += c[i];
#pragma unroll
        for (int i = 0; i < NC; ++i)
#pragma unroll
            for (int jj = i; jj < NC; ++jj)
                acc[pair_idx(i, jj)] += c[i] * c[jj];
    }

    __shared__ float red[4 * NMOM];
    const int lane = tid & 63, wave = tid >> 6;
#pragma unroll
    for (int v = 0; v < NMOM; ++v) {
        float x = acc[v];
        x += __shfl_down(x, 32);
        x += __shfl_down(x, 16);
        x += __shfl_down(x, 8);
        x += __shfl_down(x, 4);
        x += __shfl_down(x, 2);
        x += __shfl_down(x, 1);
        if (lane == 0) red[wave * NMOM + v] = x;
    }
    __syncthreads();
    if (tid < NMOM) {
        float p = red[tid] + red[NMOM + tid] + red[2 * NMOM + tid] + red[3 * NMOM + tid];
        partials[blockIdx.x * NMOM + tid] = p;
    }
}

// ---------------- Kernel 2: finalize BN stats, fold into w/bias ----------------
__global__ __launch_bounds__(320) void k_finalize(
    const float* __restrict__ partials,
    const float* __restrict__ conv_w, const float* __restrict__ conv_b,
    const float* __restrict__ gamma, const float* __restrict__ beta,
    float* __restrict__ wscaled, float* __restrict__ bias2)
{
    __shared__ double part[4][NMOM];
    __shared__ double sums[NMOM];
    const int tid = threadIdx.x;
    const int g = tid / NMOM, m = tid % NMOM;
    if (g < 4) {
        double s = 0.0;
        for (int blk = g * 64; blk < (g + 1) * 64; ++blk)
            s += (double)partials[blk * NMOM + m];
        part[g][m] = s;
    }
    __syncthreads();
    if (tid < NMOM)
        sums[tid] = part[0][tid] + part[1][tid] + part[2][tid] + part[3][tid];
    __syncthreads();
    if (tid < DD) {
        const double cnt = (double)BB * NN * KK;
        double mm[NC], w[NC];
#pragma unroll
        for (int c = 0; c < NC; ++c) {
            mm[c] = sums[c] / cnt;
            w[c] = (double)conv_w[tid * NC + c];
        }
        const double bd = (double)conv_b[tid];
        double wm = 0.0;
#pragma unroll
        for (int c = 0; c < NC; ++c) wm += w[c] * mm[c];
        const double mean = wm + bd;
        double ex2 = bd * bd + 2.0 * bd * wm;
#pragma unroll
        for (int i = 0; i < NC; ++i)
#pragma unroll
            for (int j = i; j < NC; ++j) {
                const double Mij = sums[pair_idx(i, j)] / cnt;
                ex2 += (i == j ? 1.0 : 2.0) * w[i] * w[j] * Mij;
            }
        const double var = ex2 - mean * mean;
        const double scale = (double)gamma[tid] / sqrt(var + BN_EPS);
        bias2[tid] = (float)((double)beta[tid] + (bd - mean) * scale);
#pragma unroll
        for (int c = 0; c < NC; ++c)
            wscaled[tid * NC + c] = (float)(w[c] * scale);
    }
}

// ---------------- Kernel 3: x-part, LDS-staged, long sequential write runs ----
// Block = (b, 64 consecutive n). Phase 1: compute c[10] for all 64n*16k=1024
// (n,k) pairs into LDS [ch][nk]. Phase 2: each of 4 waves owns 16 d-planes;
// per d it writes the block's 4 KiB output run with 4 back-to-back 1 KiB
// float4 stores (4x longer DRAM runs than the per-thread d-loop version).
__global__ __launch_bounds__(256) void k_x(
    const float* __restrict__ coords, const float* __restrict__ dist,
    const int* __restrict__ idx,
    const float* __restrict__ wscaled, const float* __restrict__ bias2,
    float* __restrict__ out)
{
    __shared__ float c_lds[NC][1024];   // 40 KB
    __shared__ float w_s[DD * NC];
    __shared__ float b2_s[DD];

    const int tid = threadIdx.x;
    for (int i = tid; i < DD * NC; i += 256) w_s[i] = wscaled[i];
    if (tid < DD) b2_s[tid] = bias2[tid];

    const int b  = blockIdx.x >> 9;          // 512 n-groups per batch
    const int n0 = (blockIdx.x & 511) << 6;  // 64 n per block

    // ---- Phase 1: thread tid -> n_local = tid/4, k-quad = tid%4 ----
    {
        const int n_loc = tid >> 2;
        const int k0 = (tid & 3) << 2;
        const int bn = b * NN + n0 + n_loc;

        const float* cc = coords + (size_t)bn * 3;
        const float cx = cc[0], cy = cc[1], cz = cc[2];
        const float* cb = coords + (size_t)b * NN * 3;

        const int4 j4 = *reinterpret_cast<const int4*>(idx + (size_t)bn * KK + k0);
        const float4 d4 = *reinterpret_cast<const float4*>(dist + (size_t)bn * KK + k0);
        const int js[4] = {j4.x, j4.y, j4.z, j4.w};
        const float dsv[4] = {d4.x, d4.y, d4.z, d4.w};

        float c[4][NC];
#pragma unroll
        for (int q = 0; q < 4; ++q) {
            const float* nc = cb + (size_t)js[q] * 3;
            const float nx = nc[0], ny = nc[1], nz = nc[2];
            c[q][0] = cx; c[q][1] = cy; c[q][2] = cz;
            c[q][3] = nx; c[q][4] = ny; c[q][5] = nz;
            c[q][6] = cx - nx; c[q][7] = cy - ny; c[q][8] = cz - nz;
            c[q][9] = dsv[q];
        }
        // transpose to [ch][nk]: one float4 (4 nk) per channel
#pragma unroll
        for (int ch = 0; ch < NC; ++ch) {
            float4 v{c[0][ch], c[1][ch], c[2][ch], c[3][ch]};
            *reinterpret_cast<float4*>(&c_lds[ch][tid << 2]) = v;
        }
    }
    __syncthreads();

    // ---- Phase 2: wave w owns d in [16w, 16w+16) ----
    const int lane = tid & 63, wave = tid >> 6;
    const size_t cstride = (size_t)NN * KK;
    // block's output base for d-plane d: ((b*2*DD + d) * NN + n0) * KK
    const size_t base0 = (((size_t)b * 2 * DD) * NN + n0) * KK;

#pragma unroll 2
    for (int dd = 0; dd < 16; ++dd) {
        const int d = (wave << 4) + dd;
        float wv[NC];
#pragma unroll
        for (int ch = 0; ch < NC; ++ch) wv[ch] = w_s[d * NC + ch];  // uniform -> broadcast
        const float b2 = b2_s[d];
        float* dst = out + base0 + (size_t)d * cstride;

#pragma unroll
        for (int chunk = 0; chunk < 4; ++chunk) {
            const int nk0 = (chunk << 8) + (lane << 2);
            float4 acc{b2, b2, b2, b2};
#pragma unroll
            for (int ch = 0; ch < NC; ++ch) {
                const float4 cv = *reinterpret_cast<const float4*>(&c_lds[ch][nk0]);
                const float w = wv[ch];
                acc.x += cv.x * w; acc.y += cv.y * w;
                acc.z += cv.z * w; acc.w += cv.w * w;
            }
            acc.x = fmaxf(acc.x, 0.f); acc.y = fmaxf(acc.y, 0.f);
            acc.z = fmaxf(acc.z, 0.f); acc.w = fmaxf(acc.w, 0.f);
            *reinterpret_cast<float4*>(dst + nk0) = acc;
        }
    }
}

// ---------------- Kernel 4: feature broadcast, fully sequential writes ----------------
__global__ __launch_bounds__(256) void k_feat(
    const float* __restrict__ features, float* __restrict__ out)
{
    const int t = blockIdx.x * 256 + threadIdx.x;   // 0 .. B*D*N - 1
    const float f = features[t];
    const int bd = t >> 15;                          // b*DD + d
    const int n = t & (NN - 1);
    const int b = bd >> 6;
    const int d = bd & (DD - 1);
    const size_t base = (((size_t)b * 2 * DD + DD + d) * NN + n) * KK;
    const float4 v{f, f, f, f};
    float4* p = reinterpret_cast<float4*>(out + base);
    p[0] = v; p[1] = v; p[2] = v; p[3] = v;
}

// ---------------- launch ----------------
extern "C" void kernel_launch(void* const* d_in, const int* in_sizes, int n_in,
                              void* d_out, int out_size, void* d_ws, size_t ws_size,
                              hipStream_t stream) {
    const float* coords   = (const float*)d_in[0];
    const float* features = (const float*)d_in[1];
    const float* dist     = (const float*)d_in[2];
    const float* conv_w   = (const float*)d_in[3];
    const float* conv_b   = (const float*)d_in[4];
    const float* gamma    = (const float*)d_in[5];
    const float* beta     = (const float*)d_in[6];
    const int*   idx      = (const int*)d_in[7];
    float* out = (float*)d_out;

    float* partials = (float*)d_ws;                 // 256*65 floats
    float* wscaled  = partials + NBLK1 * NMOM;      // 640 floats
    float* bias2    = wscaled + DD * NC;            // 64 floats

    k_moments<<<NBLK1, 256, 0, stream>>>(coords, dist, idx, partials);
    k_finalize<<<1, 320, 0, stream>>>(partials, conv_w, conv_b, gamma, beta,
                                      wscaled, bias2);
    k_feat<<<(BB * DD * NN) / 256, 256, 0, stream>>>(features, out);
    k_x<<<BB * (NN / 64), 256, 0, stream>>>(
        coords, dist, idx, wscaled, bias2, out);
}

// Round 7
// 614.702 us; speedup vs baseline: 1.1723x; 1.1723x over previous
//
#include <hip/hip_runtime.h>

#define BB 2
#define NN 32768
#define KK 16
#define DD 64
#define NC 10
#define NMOM 65
#define NBLK1 256
#define BN_EPS 1e-6
#define DGRP 8              // d-planes per block in k_x
#define NCH 64              // n per block in k_x
#define NCHUNKS (NN / NCH)  // 512

__host__ __device__ __forceinline__ constexpr int pair_idx(int i, int j) {
    return 10 + i * 10 - (i * (i - 1)) / 2 + (j - i);
}

// ---------------- Kernel 1: concat-vector moment reduction ----------------
__global__ __launch_bounds__(256) void k_moments(
    const float* __restrict__ coords, const float* __restrict__ dist,
    const int* __restrict__ idx, float* __restrict__ partials)
{
    const int tid = threadIdx.x;
    const int bn = blockIdx.x * 256 + tid;
    const int b = bn >> 15;

    float acc[NMOM];
#pragma unroll
    for (int v = 0; v < NMOM; ++v) acc[v] = 0.f;

    const float cx = coords[(size_t)bn * 3 + 0];
    const float cy = coords[(size_t)bn * 3 + 1];
    const float cz = coords[(size_t)bn * 3 + 2];
    const float* cb = coords + (size_t)b * NN * 3;

    for (int k = 0; k < KK; ++k) {
        const int j = idx[(size_t)bn * KK + k];
        const float nx = cb[(size_t)j * 3 + 0];
        const float ny = cb[(size_t)j * 3 + 1];
        const float nz = cb[(size_t)j * 3 + 2];
        const float dd = dist[(size_t)bn * KK + k];
        const float c[NC] = {cx, cy, cz, nx, ny, nz, cx - nx, cy - ny, cz - nz, dd};
#pragma unroll
        for (int i = 0; i < NC; ++i) acc[i] += c[i];
#pragma unroll
        for (int i = 0; i < NC; ++i)
#pragma unroll
            for (int jj = i; jj < NC; ++jj)
                acc[pair_idx(i, jj)] += c[i] * c[jj];
    }

    __shared__ float red[4 * NMOM];
    const int lane = tid & 63, wave = tid >> 6;
#pragma unroll
    for (int v = 0; v < NMOM; ++v) {
        float x = acc[v];
        x += __shfl_down(x, 32);
        x += __shfl_down(x, 16);
        x += __shfl_down(x, 8);
        x += __shfl_down(x, 4);
        x += __shfl_down(x, 2);
        x += __shfl_down(x, 1);
        if (lane == 0) red[wave * NMOM + v] = x;
    }
    __syncthreads();
    if (tid < NMOM) {
        float p = red[tid] + red[NMOM + tid] + red[2 * NMOM + tid] + red[3 * NMOM + tid];
        partials[blockIdx.x * NMOM + tid] = p;
    }
}

// ---------------- Kernel 2: finalize BN stats, fold into w/bias ----------------
__global__ __launch_bounds__(320) void k_finalize(
    const float* __restrict__ partials,
    const float* __restrict__ conv_w, const float* __restrict__ conv_b,
    const float* __restrict__ gamma, const float* __restrict__ beta,
    float* __restrict__ wscaled, float* __restrict__ bias2)
{
    __shared__ double part[4][NMOM];
    __shared__ double sums[NMOM];
    const int tid = threadIdx.x;
    const int g = tid / NMOM, m = tid % NMOM;
    if (g < 4) {
        double s = 0.0;
        for (int blk = g * 64; blk < (g + 1) * 64; ++blk)
            s += (double)partials[blk * NMOM + m];
        part[g][m] = s;
    }
    __syncthreads();
    if (tid < NMOM)
        sums[tid] = part[0][tid] + part[1][tid] + part[2][tid] + part[3][tid];
    __syncthreads();
    if (tid < DD) {
        const double cnt = (double)BB * NN * KK;
        double mm[NC], w[NC];
#pragma unroll
        for (int c = 0; c < NC; ++c) {
            mm[c] = sums[c] / cnt;
            w[c] = (double)conv_w[tid * NC + c];
        }
        const double bd = (double)conv_b[tid];
        double wm = 0.0;
#pragma unroll
        for (int c = 0; c < NC; ++c) wm += w[c] * mm[c];
        const double mean = wm + bd;
        double ex2 = bd * bd + 2.0 * bd * wm;
#pragma unroll
        for (int i = 0; i < NC; ++i)
#pragma unroll
            for (int j = i; j < NC; ++j) {
                const double Mij = sums[pair_idx(i, j)] / cnt;
                ex2 += (i == j ? 1.0 : 2.0) * w[i] * w[j] * Mij;
            }
        const double var = ex2 - mean * mean;
        const double scale = (double)gamma[tid] / sqrt(var + BN_EPS);
        bias2[tid] = (float)((double)beta[tid] + (bd - mean) * scale);
#pragma unroll
        for (int c = 0; c < NC; ++c)
            wscaled[tid * NC + c] = (float)(w[c] * scale);
    }
}

// ---------------- Kernel 3: x-part, dispatch-throttled monotonic writes ------
// Block = (dgrp, b, nc) with nc FASTEST in blockIdx -> consecutive blocks
// extend the same 8 d-planes at consecutive n: narrow sequential write front
// (k_feat-like). 8192 blocks (32/CU) so dispatch order throttles execution.
// Each thread builds c[4][10] for its (n, k-quad) once, then stores one
// float4 per d-plane. Per plane per block: 4 KiB contiguous.
__global__ __launch_bounds__(256) void k_x(
    const float* __restrict__ coords, const float* __restrict__ dist,
    const int* __restrict__ idx,
    const float* __restrict__ wscaled, const float* __restrict__ bias2,
    float* __restrict__ out)
{
    __shared__ float w_s[DD * NC];
    __shared__ float b2_s[DD];
    const int tid = threadIdx.x;
    for (int i = tid; i < DD * NC; i += 256) w_s[i] = wscaled[i];
    if (tid < DD) b2_s[tid] = bias2[tid];
    __syncthreads();

    const int nc   = blockIdx.x & (NCHUNKS - 1);          // fastest
    const int b    = (blockIdx.x >> 9) & 1;
    const int dgrp = blockIdx.x >> 10;                    // 0..7

    const int n_loc = tid >> 2;
    const int k0 = (tid & 3) << 2;
    const int n = nc * NCH + n_loc;
    const int bn = b * NN + n;

    const float* cc = coords + (size_t)bn * 3;
    const float cx = cc[0], cy = cc[1], cz = cc[2];
    const float* cb = coords + (size_t)b * NN * 3;

    const int4 j4 = *reinterpret_cast<const int4*>(idx + (size_t)bn * KK + k0);
    const float4 d4 = *reinterpret_cast<const float4*>(dist + (size_t)bn * KK + k0);
    const int js[4] = {j4.x, j4.y, j4.z, j4.w};
    const float dsv[4] = {d4.x, d4.y, d4.z, d4.w};

    float c[4][NC];
#pragma unroll
    for (int q = 0; q < 4; ++q) {
        const float* nc2 = cb + (size_t)js[q] * 3;
        const float nx = nc2[0], ny = nc2[1], nz = nc2[2];
        c[q][0] = cx; c[q][1] = cy; c[q][2] = cz;
        c[q][3] = nx; c[q][4] = ny; c[q][5] = nz;
        c[q][6] = cx - nx; c[q][7] = cy - ny; c[q][8] = cz - nz;
        c[q][9] = dsv[q];
    }

    const size_t cstride = (size_t)NN * KK;
    const size_t base = ((size_t)b * 2 * DD) * cstride + (size_t)n * KK + k0;

#pragma unroll
    for (int dd = 0; dd < DGRP; ++dd) {
        const int d = dgrp * DGRP + dd;
        const float b2 = b2_s[d];
        float r0 = b2, r1 = b2, r2 = b2, r3 = b2;
#pragma unroll
        for (int ch = 0; ch < NC; ++ch) {
            const float w = w_s[d * NC + ch];
            r0 += c[0][ch] * w;
            r1 += c[1][ch] * w;
            r2 += c[2][ch] * w;
            r3 += c[3][ch] * w;
        }
        float4 r;
        r.x = fmaxf(r0, 0.f); r.y = fmaxf(r1, 0.f);
        r.z = fmaxf(r2, 0.f); r.w = fmaxf(r3, 0.f);
        *reinterpret_cast<float4*>(out + base + (size_t)d * cstride) = r;
    }
}

// ---------------- Kernel 4: feature broadcast, fully sequential writes -------
__global__ __launch_bounds__(256) void k_feat(
    const float* __restrict__ features, float* __restrict__ out)
{
    const int t = blockIdx.x * 256 + threadIdx.x;   // 0 .. B*D*N - 1
    const float f = features[t];
    const int bd = t >> 15;
    const int n = t & (NN - 1);
    const int b = bd >> 6;
    const int d = bd & (DD - 1);
    const size_t base = (((size_t)b * 2 * DD + DD + d) * NN + n) * KK;
    const float4 v{f, f, f, f};
    float4* p = reinterpret_cast<float4*>(out + base);
    p[0] = v; p[1] = v; p[2] = v; p[3] = v;
}

// ---------------- launch ----------------
extern "C" void kernel_launch(void* const* d_in, const int* in_sizes, int n_in,
                              void* d_out, int out_size, void* d_ws, size_t ws_size,
                              hipStream_t stream) {
    const float* coords   = (const float*)d_in[0];
    const float* features = (const float*)d_in[1];
    const float* dist     = (const float*)d_in[2];
    const float* conv_w   = (const float*)d_in[3];
    const float* conv_b   = (const float*)d_in[4];
    const float* gamma    = (const float*)d_in[5];
    const float* beta     = (const float*)d_in[6];
    const int*   idx      = (const int*)d_in[7];
    float* out = (float*)d_out;

    float* partials = (float*)d_ws;
    float* wscaled  = partials + NBLK1 * NMOM;
    float* bias2    = wscaled + DD * NC;

    k_moments<<<NBLK1, 256, 0, stream>>>(coords, dist, idx, partials);
    k_finalize<<<1, 320, 0, stream>>>(partials, conv_w, conv_b, gamma, beta,
                                      wscaled, bias2);
    k_feat<<<(BB * DD * NN) / 256, 256, 0, stream>>>(features, out);
    k_x<<<(DD / DGRP) * BB * NCHUNKS, 256, 0, stream>>>(
        coords, dist, idx, wscaled, bias2, out);
}